// Round 12
// baseline (552.520 us; speedup 1.0000x reference)
//
#include <hip/hip_runtime.h>
#include <hip/hip_bf16.h>

// All float tensors are fp32 (TRUE fp32 values — selection must use exact fp32;
// bf16-level VALUE error is only tolerable in the MLP). fps_idx int32.

typedef __attribute__((ext_vector_type(8))) short short8;
typedef __attribute__((ext_vector_type(4))) float float4v;

constexpr int BB = 16, NN = 4096, SS = 1024, DD = 64, KK = 32;
constexpr int PP = BB * SS * KK;            // 524288 grouped points
constexpr int NG = BB * SS;                 // 16384 query groups
constexpr float EPSF = 1e-5f;
constexpr int CAND_MAX = 640;               // per-wave kNN candidate cap
constexpr int QPB = 8;                      // queries (waves) per select block

// Workspace layout (float offsets).
constexpr int WS_IDX   = 0;                    // ushort[PP]
constexpr int WS_NXYZ  = PP / 2;               // float[NG*3]
constexpr int WS_W0PK  = WS_NXYZ + NG*3;       // ushort[6144]  W0' frag image (K=96: feat + xyz hi/lo)
constexpr int WS_W1PK  = WS_W0PK + 3072;       // ushort[4096]  W1' frag image (K=64, bf16-only)
constexpr int WS_W2PK  = WS_W1PK + 2048;       // ushort[8192]  W2' frag image (K=64, bf16-only)
constexpr int WS_W1PKD = WS_W2PK + 4096;       // ushort[8192]  W1 dup image (K=128 hi/lo, fallback)
constexpr int WS_W2PKD = WS_W1PKD + 4096;      // ushort[16384] W2 dup image (K=128 hi/lo, fallback)
constexpr int WS_SUMS  = WS_W2PKD + 8192;      // float[512]
constexpr int WS_SCALE = WS_SUMS + 512;        // float[512]
constexpr int WS_H1    = WS_SCALE + 512;       // ushort[PP*64] pre-BN H1 (bf16)
constexpr int WS_H2    = WS_H1 + PP*32;        // ushort[PP*64] pre-BN H2 (bf16)
constexpr int WS_END   = WS_H2 + PP*32;
constexpr size_t WS_FAST_BYTES = (size_t)WS_END * 4;

__device__ __forceinline__ unsigned rtne16(float x) {
    unsigned b = __float_as_uint(x);
    return (b + 0x7fffu + ((b >> 16) & 1u)) >> 16;
}
// bf16 RTNE bits left in [31:16]
__device__ __forceinline__ unsigned rtneb(float r) {
    unsigned b = __float_as_uint(r);
    return b + 0x7fffu + ((b >> 16) & 1u);
}
// pack: low16 = a[31:16], high16 = b[31:16]
__device__ __forceinline__ unsigned pk2r(unsigned a, unsigned b) {
    return __builtin_amdgcn_perm(a, b, 0x03020706u);
}
__device__ __forceinline__ unsigned pk2f(float a, float b) {
    return pk2r(__float_as_uint(a), __float_as_uint(b));
}
// unpack bf16 pair, apply BN+ReLU per element, repack to bf16 pair
__device__ __forceinline__ unsigned bnpack(unsigned u, float sce, float sfe,
                                           float sco, float sfo) {
    float fe = __uint_as_float(u << 16);
    float fo = __uint_as_float(u & 0xffff0000u);
    float ze = fmaxf(fmaf(fe, sce, sfe), 0.f);
    float zo = fmaxf(fmaf(fo, sco, sfo), 0.f);
    return pk2r(rtneb(ze), rtneb(zo));
}

union UF { uint4 u; short8 s; };
__device__ __forceinline__ short8 ldw(const uint4* __restrict__ p, int idx) {
    UF u; u.u = p[idx]; return u.s;
}

#define LDS_SYNC() asm volatile("s_waitcnt lgkmcnt(0)" ::: "memory")

// ---------------- prep: frag-major bf16 weight images + zero stats ----------------
__global__ void k_prep(const float* __restrict__ w0, const float* __restrict__ w1,
                       const float* __restrict__ w2, float* __restrict__ ws) {
    const int t = threadIdx.x;
    ushort* w0pk = (ushort*)(ws + WS_W0PK);
    for (int i = t; i < 6144; i += 256) {        // [Nt(4)][Ks(3)][lane(64)][j(8)]
        int j = i & 7, l = (i >> 3) & 63, Ks = (i >> 9) % 3, Nt = i / 1536;
        int o = Nt*16 + (l & 15);
        int k = Ks*32 + (l >> 4)*8 + j;
        float v = 0.f;
        if (k < 64)      v = w0[o*67 + 3 + k];
        else if (k < 67) v = w0[o*67 + (k - 64)];     // xyz hi
        else if (k < 70) v = w0[o*67 + (k - 67)];     // xyz lo (same weights)
        w0pk[i] = (ushort)rtne16(v);
    }
    ushort* w1pk = (ushort*)(ws + WS_W1PK);
    for (int i = t; i < 4096; i += 256) {        // [Nt(4)][Ks(2)][lane][j], K=64
        int j = i & 7, l = (i >> 3) & 63, Ks = (i >> 9) & 1, Nt = i >> 10;
        int o = Nt*16 + (l & 15);
        int k = Ks*32 + (l >> 4)*8 + j;
        w1pk[i] = (ushort)rtne16(w1[o*64 + k]);
    }
    ushort* w2pk = (ushort*)(ws + WS_W2PK);
    for (int i = t; i < 8192; i += 256) {        // [Nt(8)][Ks(2)][lane][j], K=64
        int j = i & 7, l = (i >> 3) & 63, Ks = (i >> 9) & 1, Nt = i >> 10;
        int o = Nt*16 + (l & 15);
        int k = Ks*32 + (l >> 4)*8 + j;
        w2pk[i] = (ushort)rtne16(w2[o*64 + k]);
    }
    // fallback dup images (K=128 hi/lo interleaved)
    ushort* w1pd = (ushort*)(ws + WS_W1PKD);
    for (int i = t; i < 8192; i += 256) {        // [Nt(4)][Ks(4)][lane][j]
        int j = i & 7, l = (i >> 3) & 63, Ks = (i >> 9) & 3, Nt = i >> 11;
        int o = Nt*16 + (l & 15);
        int c = (Ks*32 + (l >> 4)*8 + j) >> 1;
        w1pd[i] = (ushort)rtne16(w1[o*64 + c]);
    }
    ushort* w2pd = (ushort*)(ws + WS_W2PKD);
    for (int i = t; i < 16384; i += 256) {       // [Nt(8)][Ks(4)][lane][j]
        int j = i & 7, l = (i >> 3) & 63, Ks = (i >> 9) & 3, Nt = i >> 11;
        int o = Nt*16 + (l & 15);
        int c = (Ks*32 + (l >> 4)*8 + j) >> 1;
        w2pd[i] = (ushort)rtne16(w2[o*64 + c]);
    }
    for (int i = t; i < 512; i += 256) ws[WS_SUMS + i] = 0.f;
}

// ---------------- select: exact top-32 nearest neighbors per query ----------------
// 8 waves (512 threads) share a float4 tile (x,y,z,|p|^2) — |p|^2 precomputed
// at tile load with the exact reference rounding chain, so keys are bit-identical
// to the proven R7/R8 path but each keyAt is 1 ds_read_b128 + 8 VALU.
// Phase A stores the 64 keys/lane in VGPRs (single eval per key); candidates are
// ballot-compacted as INDICES only (10 KB LDS); fast path recomputes <=10
// keys/lane from the tile, binary-searches T, and emits with exact top_k ties.
// LDS 74 KB -> 2 blocks x 8 waves = 16 waves/CU; VGPR capped at 128 (no spill).
__global__ __launch_bounds__(512, 4) void k_select(
    const float* __restrict__ xyz, const int* __restrict__ fps,
    float* __restrict__ out_xyz, float* __restrict__ ws)
{
    __shared__ float4 sp[NN];                   // 64 KB exact fp32 x,y,z,|p|^2
    __shared__ ushort cbi[QPB][CAND_MAX];       // 10 KB candidate indices
    const int tid = threadIdx.x;
    const int qb = blockIdx.x * QPB;
    const int b  = qb >> 10;
    const float* __restrict__ xb = xyz + (long)b * NN * 3;
    for (int i = tid; i < NN; i += 512) {
        float x = xb[i*3 + 0], y = xb[i*3 + 1], z = xb[i*3 + 2];
        float pw = __fadd_rn(__fadd_rn(__fmul_rn(x,x), __fmul_rn(y,y)), __fmul_rn(z,z));
        sp[i] = make_float4(x, y, z, pw);
    }
    __syncthreads();

    const int wave = tid >> 6, lane = tid & 63;
    const int q = qb + wave;
    const int nq = fps[q];
    const float4 qp = sp[nq];                   // broadcast read (free)
    const float qx = qp.x, qy = qp.y, qz = qp.z, qw = qp.w;

    float* nxyz = ws + WS_NXYZ;
    unsigned short* idx_ws = (unsigned short*)ws;
    if (lane < 3) {
        float v = (lane == 0) ? qx : ((lane == 1) ? qy : qz);
        out_xyz[q*3 + lane] = v;
        nxyz[q*3 + lane] = v;
    }

    // key for tile point n: exact fp32, deterministic op sequence
    auto keyAt = [&](int n) -> unsigned {
        float4 pp = sp[n];
        float dot = fmaf(qx, pp.x, 0.f);
        dot = fmaf(qy, pp.y, dot);
        dot = fmaf(qz, pp.z, dot);
        float d = __fadd_rn(__fadd_rn(__fmul_rn(-2.0f, dot), qw), pp.w);
        unsigned u = __float_as_uint(d);
        return u ^ (unsigned)(((int)u >> 31) | 0x80000000);
    };

    // phase A: 64 keys/lane, stored in VGPRs (one eval per key)
    unsigned key[64];
    unsigned lmin = 0xFFFFFFFFu, lmax = 0u;
    #pragma unroll
    for (int i = 0; i < 64; ++i) {
        unsigned k = keyAt(i*64 + lane);
        key[i] = k;
        lmin = min(lmin, k); lmax = max(lmax, k);
    }
    unsigned gmin = lmin, gmax = lmax, Bv = lmin;
    #pragma unroll
    for (int off = 32; off > 0; off >>= 1) {
        gmin = min(gmin, (unsigned)__shfl_xor((int)gmin, off));
        gmax = max(gmax, (unsigned)__shfl_xor((int)gmax, off));
        Bv   = max(Bv,   (unsigned)__shfl_xor((int)Bv,   off));
    }
    // Bv = max of lane minima >= 64th smallest key >= T

    const unsigned long long lmask = (1ull << lane) - 1ull;
    ushort* ciw = cbi[wave];

    // compaction: candidate indices (<= Bv), ascending global index
    int cnt = 0;
    #pragma unroll
    for (int i = 0; i < 64; ++i) {
        bool pr = key[i] <= Bv;
        unsigned long long m = __ballot(pr);
        int pos = cnt + (int)__popcll(m & lmask);
        if (pr && pos < CAND_MAX) ciw[pos] = (ushort)(i*64 + lane);
        cnt += (int)__popcll(m);
    }
    const int base = q * KK;

    if (cnt <= CAND_MAX) {
        LDS_SYNC();
        // candidates into regs (static 10 slots, keys recomputed from tile)
        unsigned cr[10]; ushort ir[10];
        #pragma unroll
        for (int r = 0; r < 10; ++r) {
            int j = r*64 + lane;
            bool v = j < cnt;
            ushort idx = v ? ciw[j] : (ushort)0;
            ir[r] = idx;
            cr[r] = v ? keyAt(idx) : 0xFFFFFFFFu;
        }
        // binary search smallest T in [gmin, Bv] with count(<=T) >= 32
        unsigned lo = gmin, hi = Bv;
        while (lo < hi) {
            unsigned mid = lo + ((hi - lo) >> 1);
            int c = 0;
            #pragma unroll
            for (int r = 0; r < 10; ++r)
                c += (int)__popcll(__ballot(cr[r] <= mid));
            if (c >= 32) hi = mid; else lo = mid + 1;
        }
        const unsigned T = lo;

        int c2 = 0;
        #pragma unroll
        for (int r = 0; r < 10; ++r) {           // strictly closer (count < 32)
            bool pr = cr[r] < T;
            unsigned long long m = __ballot(pr);
            if (pr) idx_ws[base + c2 + (int)__popcll(m & lmask)] = ir[r];
            c2 += (int)__popcll(m);
        }
        #pragma unroll
        for (int r = 0; r < 10; ++r) {           // ties, smallest index first
            bool pr = cr[r] == T;
            unsigned long long m = __ballot(pr);
            int pos = c2 + (int)__popcll(m & lmask);
            if (pr && pos < KK) idx_ws[base + pos] = ir[r];
            c2 += (int)__popcll(m);
        }
    } else {
        // ultra-rare fallback: full-range in-register search (keys stored)
        unsigned lo = gmin, hi = gmax;
        while (lo < hi) {
            unsigned mid = lo + ((hi - lo) >> 1);
            int c = 0;
            #pragma unroll
            for (int i = 0; i < 64; ++i)
                c += (int)__popcll(__ballot(key[i] <= mid));
            if (c >= 32) hi = mid; else lo = mid + 1;
        }
        const unsigned T = lo;
        int c2 = 0;
        #pragma unroll
        for (int i = 0; i < 64; ++i) {
            bool pr = key[i] < T;
            unsigned long long m = __ballot(pr);
            if (pr) idx_ws[base + c2 + (int)__popcll(m & lmask)] = (ushort)(i*64 + lane);
            c2 += (int)__popcll(m);
        }
        #pragma unroll
        for (int i = 0; i < 64; ++i) {
            bool pr = key[i] == T;
            unsigned long long m = __ballot(pr);
            int pos = c2 + (int)__popcll(m & lmask);
            if (pr && pos < KK) idx_ws[base + pos] = (ushort)(i*64 + lane);
            c2 += (int)__popcll(m);
        }
    }
}

// ================= fast path: materialized pre-BN activations =================
// H layout: ushort bf16 H[p][c], p = grouped point (g*32 + m). A-frag reads and
// C-writes are coalesced; no LDS roundtrip, no recompute.

// ---- pass A: gather + GEMM1 -> H1 + stats1 ----
__global__ __launch_bounds__(256, 3) void k_g1(
    const float* __restrict__ xyz, const float* __restrict__ pts,
    const float* __restrict__ b0, float* __restrict__ ws,
    ushort* __restrict__ h1)
{
    __shared__ float rbuf[4][128];
    const int tid = threadIdx.x;
    const int wv = tid >> 6, l = tid & 63, ln = l & 15, q8 = l >> 4;

    const ushort* idxw = (const ushort*)ws;
    const float* nxyz = ws + WS_NXYZ;
    float* sums = ws + WS_SUMS;
    const uint4* w0f = (const uint4*)(ws + WS_W0PK);

    short8 w0r[12];
    #pragma unroll
    for (int t = 0; t < 12; ++t) w0r[t] = ldw(w0f, t*64 + l);
    float b0v[4];
    #pragma unroll
    for (int n = 0; n < 4; ++n) b0v[n] = b0[n*16 + ln];

    float s[4] = {0,0,0,0}, sq[4] = {0,0,0,0};
    const int gbase = blockIdx.x*4 + wv;

    // prefetch gather indices one iteration ahead (breaks idx->gather chain)
    int nbn[2];
    #pragma unroll
    for (int Mt = 0; Mt < 2; ++Mt) nbn[Mt] = idxw[gbase*32 + Mt*16 + ln];

    for (int it = 0; it < 4; ++it) {
        const int g = gbase + it*4096;
        const float nqx = nxyz[g*3+0], nqy = nxyz[g*3+1], nqz = nxyz[g*3+2];
        int nbc[2] = {nbn[0], nbn[1]};
        if (it < 3) {
            #pragma unroll
            for (int Mt = 0; Mt < 2; ++Mt)
                nbn[Mt] = idxw[(g + 4096)*32 + Mt*16 + ln];
        }

        short8 a1[2][3];
        #pragma unroll
        for (int Mt = 0; Mt < 2; ++Mt) {
            int row = (g >> 10)*NN + nbc[Mt];
            const float* p = pts + row*64 + q8*8;
            float4 f0 = *(const float4*)p;
            float4 f1 = *(const float4*)(p + 4);
            float4 f2 = *(const float4*)(p + 32);
            float4 f3 = *(const float4*)(p + 36);
            UF t0, t1;
            t0.u.x = pk2f(f0.x, f0.y); t0.u.y = pk2f(f0.z, f0.w);
            t0.u.z = pk2f(f1.x, f1.y); t0.u.w = pk2f(f1.z, f1.w);
            a1[Mt][0] = t0.s;
            t1.u.x = pk2f(f2.x, f2.y); t1.u.y = pk2f(f2.z, f2.w);
            t1.u.z = pk2f(f3.x, f3.y); t1.u.w = pk2f(f3.z, f3.w);
            a1[Mt][1] = t1.s;
            UF x; x.u = make_uint4(0,0,0,0);
            if (q8 == 0) {
                float vx = xyz[row*3+0] - nqx;
                float vy = xyz[row*3+1] - nqy;
                float vz = xyz[row*3+2] - nqz;
                unsigned bx = __float_as_uint(vx), by = __float_as_uint(vy), bz = __float_as_uint(vz);
                float rx = vx - __uint_as_float(bx & 0xffff0000u);
                float ry = vy - __uint_as_float(by & 0xffff0000u);
                float rz = vz - __uint_as_float(bz & 0xffff0000u);
                x.u.x = pk2r(bx, by);
                x.u.y = pk2r(bz, rtneb(rx));
                x.u.z = pk2r(rtneb(ry), rtneb(rz));
            }
            a1[Mt][2] = x.s;
        }

        float4v acc[2][4];
        #pragma unroll
        for (int Mt = 0; Mt < 2; ++Mt)
            #pragma unroll
            for (int Nt = 0; Nt < 4; ++Nt)
                acc[Mt][Nt] = (float4v){b0v[Nt], b0v[Nt], b0v[Nt], b0v[Nt]};
        #pragma unroll
        for (int Ks = 0; Ks < 3; ++Ks)
            #pragma unroll
            for (int Nt = 0; Nt < 4; ++Nt)
                #pragma unroll
                for (int Mt = 0; Mt < 2; ++Mt)
                    acc[Mt][Nt] = __builtin_amdgcn_mfma_f32_16x16x32_bf16(
                        a1[Mt][Ks], w0r[Nt*3 + Ks], acc[Mt][Nt], 0, 0, 0);

        #pragma unroll
        for (int Mt = 0; Mt < 2; ++Mt)
            #pragma unroll
            for (int Nt = 0; Nt < 4; ++Nt)
                #pragma unroll
                for (int r = 0; r < 4; ++r) {
                    float h = acc[Mt][Nt][r];
                    s[Nt] += h; sq[Nt] += h*h;
                    h1[(g*32 + Mt*16 + q8*4 + r)*64 + Nt*16 + ln] = (ushort)rtne16(h);
                }
    }

    #pragma unroll
    for (int t = 0; t < 4; ++t) {
        float a = s[t], b = sq[t];
        a += __shfl_xor(a, 16); a += __shfl_xor(a, 32);
        b += __shfl_xor(b, 16); b += __shfl_xor(b, 32);
        if (l < 16) { rbuf[wv][t*16 + l] = a; rbuf[wv][64 + t*16 + l] = b; }
    }
    __syncthreads();
    if (wv == 0 && l < 16) {
        #pragma unroll
        for (int t = 0; t < 4; ++t) {
            float a = rbuf[0][t*16+l] + rbuf[1][t*16+l] + rbuf[2][t*16+l] + rbuf[3][t*16+l];
            float b = rbuf[0][64+t*16+l] + rbuf[1][64+t*16+l] + rbuf[2][64+t*16+l] + rbuf[3][64+t*16+l];
            atomicAdd(&sums[t*16 + l], a);
            atomicAdd(&sums[64 + t*16 + l], b);
        }
    }
}

// ---- pass B: H1 -> BN1+ReLU -> GEMM2 -> H2 + stats2 ----
__global__ __launch_bounds__(256, 4) void k_g2(
    const float* __restrict__ b1, float* __restrict__ ws,
    const ushort* __restrict__ h1, ushort* __restrict__ h2)
{
    __shared__ float rbuf[4][128];
    const int tid = threadIdx.x;
    const int wv = tid >> 6, l = tid & 63, ln = l & 15, q8 = l >> 4;

    const float* scl = ws + WS_SCALE;
    float* sums = ws + WS_SUMS;
    const uint4* w1f = (const uint4*)(ws + WS_W1PK);

    float b1v[4];
    #pragma unroll
    for (int n = 0; n < 4; ++n) b1v[n] = b1[n*16 + ln];
    float4 sc[2][2], sf[2][2];
    #pragma unroll
    for (int Ks = 0; Ks < 2; ++Ks) {
        sc[Ks][0] = *(const float4*)&scl[Ks*32 + q8*8];
        sc[Ks][1] = *(const float4*)&scl[Ks*32 + q8*8 + 4];
        sf[Ks][0] = *(const float4*)&scl[64 + Ks*32 + q8*8];
        sf[Ks][1] = *(const float4*)&scl[64 + Ks*32 + q8*8 + 4];
    }

    float s[4] = {0,0,0,0}, sq[4] = {0,0,0,0};
    const int gbase = blockIdx.x*4 + wv;

    for (int it = 0; it < 4; ++it) {
        const int g = gbase + it*4096;

        short8 a[2][2];
        #pragma unroll
        for (int Mt = 0; Mt < 2; ++Mt)
            #pragma unroll
            for (int Ks = 0; Ks < 2; ++Ks) {
                uint4 hv = *(const uint4*)&h1[(g*32 + Mt*16 + ln)*64 + Ks*32 + q8*8];
                UF t;
                t.u.x = bnpack(hv.x, sc[Ks][0].x, sf[Ks][0].x, sc[Ks][0].y, sf[Ks][0].y);
                t.u.y = bnpack(hv.y, sc[Ks][0].z, sf[Ks][0].z, sc[Ks][0].w, sf[Ks][0].w);
                t.u.z = bnpack(hv.z, sc[Ks][1].x, sf[Ks][1].x, sc[Ks][1].y, sf[Ks][1].y);
                t.u.w = bnpack(hv.w, sc[Ks][1].z, sf[Ks][1].z, sc[Ks][1].w, sf[Ks][1].w);
                a[Mt][Ks] = t.s;
            }

        float4v acc[2][4];
        #pragma unroll
        for (int Mt = 0; Mt < 2; ++Mt)
            #pragma unroll
            for (int Nt = 0; Nt < 4; ++Nt)
                acc[Mt][Nt] = (float4v){b1v[Nt], b1v[Nt], b1v[Nt], b1v[Nt]};
        #pragma unroll
        for (int Ks = 0; Ks < 2; ++Ks)
            #pragma unroll
            for (int Nt = 0; Nt < 4; ++Nt) {
                short8 bf = ldw(w1f, (Nt*2 + Ks)*64 + l);
                #pragma unroll
                for (int Mt = 0; Mt < 2; ++Mt)
                    acc[Mt][Nt] = __builtin_amdgcn_mfma_f32_16x16x32_bf16(
                        a[Mt][Ks], bf, acc[Mt][Nt], 0, 0, 0);
            }

        #pragma unroll
        for (int Mt = 0; Mt < 2; ++Mt)
            #pragma unroll
            for (int Nt = 0; Nt < 4; ++Nt)
                #pragma unroll
                for (int r = 0; r < 4; ++r) {
                    float h = acc[Mt][Nt][r];
                    s[Nt] += h; sq[Nt] += h*h;
                    h2[(g*32 + Mt*16 + q8*4 + r)*64 + Nt*16 + ln] = (ushort)rtne16(h);
                }
    }

    #pragma unroll
    for (int t = 0; t < 4; ++t) {
        float a = s[t], b = sq[t];
        a += __shfl_xor(a, 16); a += __shfl_xor(a, 32);
        b += __shfl_xor(b, 16); b += __shfl_xor(b, 32);
        if (l < 16) { rbuf[wv][t*16 + l] = a; rbuf[wv][64 + t*16 + l] = b; }
    }
    __syncthreads();
    if (wv == 0 && l < 16) {
        #pragma unroll
        for (int t = 0; t < 4; ++t) {
            float a = rbuf[0][t*16+l] + rbuf[1][t*16+l] + rbuf[2][t*16+l] + rbuf[3][t*16+l];
            float b = rbuf[0][64+t*16+l] + rbuf[1][64+t*16+l] + rbuf[2][64+t*16+l] + rbuf[3][64+t*16+l];
            atomicAdd(&sums[128 + t*16 + l], a);
            atomicAdd(&sums[192 + t*16 + l], b);
        }
    }
}

// ---- pass C: H2 -> BN2+ReLU -> GEMM3 -> stats3 + pre-BN pool -> out ----
__global__ __launch_bounds__(256, 3) void k_g3(
    const float* __restrict__ b2, const float* __restrict__ g2,
    float* __restrict__ ws, const ushort* __restrict__ h2,
    float* __restrict__ out_pts)
{
    __shared__ float rbuf[4][256];
    const int tid = threadIdx.x;
    const int wv = tid >> 6, l = tid & 63, ln = l & 15, q8 = l >> 4;

    const float* scl = ws + WS_SCALE;
    float* sums = ws + WS_SUMS;
    const uint4* w2f = (const uint4*)(ws + WS_W2PK);

    float b2v[8], g2v[8];
    #pragma unroll
    for (int n = 0; n < 8; ++n) { b2v[n] = b2[n*16 + ln]; g2v[n] = g2[n*16 + ln]; }
    float4 sc[2][2], sf[2][2];
    #pragma unroll
    for (int Ks = 0; Ks < 2; ++Ks) {
        sc[Ks][0] = *(const float4*)&scl[128 + Ks*32 + q8*8];
        sc[Ks][1] = *(const float4*)&scl[128 + Ks*32 + q8*8 + 4];
        sf[Ks][0] = *(const float4*)&scl[192 + Ks*32 + q8*8];
        sf[Ks][1] = *(const float4*)&scl[192 + Ks*32 + q8*8 + 4];
    }

    float s[8] = {0,0,0,0,0,0,0,0}, sq[8] = {0,0,0,0,0,0,0,0};
    const int gbase = blockIdx.x*4 + wv;

    for (int it = 0; it < 4; ++it) {
        const int g = gbase + it*4096;

        short8 a[2][2];
        #pragma unroll
        for (int Mt = 0; Mt < 2; ++Mt)
            #pragma unroll
            for (int Ks = 0; Ks < 2; ++Ks) {
                uint4 hv = *(const uint4*)&h2[(g*32 + Mt*16 + ln)*64 + Ks*32 + q8*8];
                UF t;
                t.u.x = bnpack(hv.x, sc[Ks][0].x, sf[Ks][0].x, sc[Ks][0].y, sf[Ks][0].y);
                t.u.y = bnpack(hv.y, sc[Ks][0].z, sf[Ks][0].z, sc[Ks][0].w, sf[Ks][0].w);
                t.u.z = bnpack(hv.z, sc[Ks][1].x, sf[Ks][1].x, sc[Ks][1].y, sf[Ks][1].y);
                t.u.w = bnpack(hv.w, sc[Ks][1].z, sf[Ks][1].z, sc[Ks][1].w, sf[Ks][1].w);
                a[Mt][Ks] = t.s;
            }

        float4v acc[2][8];
        #pragma unroll
        for (int Mt = 0; Mt < 2; ++Mt)
            #pragma unroll
            for (int Nt = 0; Nt < 8; ++Nt)
                acc[Mt][Nt] = (float4v){b2v[Nt], b2v[Nt], b2v[Nt], b2v[Nt]};
        #pragma unroll
        for (int Ks = 0; Ks < 2; ++Ks)
            #pragma unroll
            for (int Nt = 0; Nt < 8; ++Nt) {
                short8 bf = ldw(w2f, (Nt*2 + Ks)*64 + l);
                #pragma unroll
                for (int Mt = 0; Mt < 2; ++Mt)
                    acc[Mt][Nt] = __builtin_amdgcn_mfma_f32_16x16x32_bf16(
                        a[Mt][Ks], bf, acc[Mt][Nt], 0, 0, 0);
            }

        float mm[8];
        #pragma unroll
        for (int Nt = 0; Nt < 8; ++Nt) {
            const bool pos = g2v[Nt] >= 0.f;
            float m = acc[0][Nt][0];
            #pragma unroll
            for (int Mt = 0; Mt < 2; ++Mt)
                #pragma unroll
                for (int r = 0; r < 4; ++r) {
                    float h = acc[Mt][Nt][r];
                    s[Nt] += h; sq[Nt] += h*h;
                    if (!(Mt == 0 && r == 0))
                        m = pos ? fmaxf(m, h) : fminf(m, h);
                }
            float o = __shfl_xor(m, 16); m = pos ? fmaxf(m, o) : fminf(m, o);
            o = __shfl_xor(m, 32);       m = pos ? fmaxf(m, o) : fminf(m, o);
            mm[Nt] = m;
        }
        if (l < 16) {
            #pragma unroll
            for (int Nt = 0; Nt < 8; ++Nt)
                out_pts[(long)g*128 + Nt*16 + l] = mm[Nt];
        }
    }

    #pragma unroll
    for (int t = 0; t < 8; ++t) {
        float a = s[t], b = sq[t];
        a += __shfl_xor(a, 16); a += __shfl_xor(a, 32);
        b += __shfl_xor(b, 16); b += __shfl_xor(b, 32);
        if (l < 16) { rbuf[wv][t*16 + l] = a; rbuf[wv][128 + t*16 + l] = b; }
    }
    __syncthreads();
    if (wv == 0 && l < 16) {
        #pragma unroll
        for (int t = 0; t < 8; ++t) {
            float a = rbuf[0][t*16+l] + rbuf[1][t*16+l] + rbuf[2][t*16+l] + rbuf[3][t*16+l];
            float b = rbuf[0][128+t*16+l] + rbuf[1][128+t*16+l] + rbuf[2][128+t*16+l] + rbuf[3][128+t*16+l];
            atomicAdd(&sums[256 + t*16 + l], a);
            atomicAdd(&sums[384 + t*16 + l], b);
        }
    }
}

// ================= fallback path (small ws): recompute, R4-style =================
template<int STAGE>
__global__ __launch_bounds__(256, 2) void k_passF(
    const float* __restrict__ xyz, const float* __restrict__ pts,
    const float* __restrict__ b0, const float* __restrict__ b1,
    const float* __restrict__ b2, const float* __restrict__ g2,
    float* __restrict__ ws, float* __restrict__ out_pts)
{
    __shared__ __align__(16) ushort zb[(STAGE >= 2) ? 4*32*136 : 8];
    const int tid = threadIdx.x;
    const int wv = tid >> 6, l = tid & 63, ln = l & 15, q8 = l >> 4;
    ushort* zw = &zb[(STAGE >= 2) ? wv*32*136 : 0];

    const ushort* idxw = (const ushort*)ws;
    const float* nxyz = ws + WS_NXYZ;
    const float* scl  = ws + WS_SCALE;
    float*       sums = ws + WS_SUMS;
    const uint4* w0f = (const uint4*)(ws + WS_W0PK);
    const uint4* w1f = (const uint4*)(ws + WS_W1PKD);
    const uint4* w2f = (const uint4*)(ws + WS_W2PKD);

    float b0v[4];
    #pragma unroll
    for (int n = 0; n < 4; ++n) b0v[n] = b0[n*16 + ln];
    float sc1v[4], sf1v[4], b1v[4];
    if constexpr (STAGE >= 2) {
        #pragma unroll
        for (int n = 0; n < 4; ++n) {
            sc1v[n] = scl[n*16 + ln]; sf1v[n] = scl[64 + n*16 + ln];
            b1v[n] = b1[n*16 + ln];
        }
    }
    float sc2v[4], sf2v[4], b2v[8], g2v[8];
    if constexpr (STAGE >= 3) {
        #pragma unroll
        for (int n = 0; n < 4; ++n) {
            sc2v[n] = scl[128 + n*16 + ln]; sf2v[n] = scl[192 + n*16 + ln];
        }
        #pragma unroll
        for (int n = 0; n < 8; ++n) { b2v[n] = b2[n*16 + ln]; g2v[n] = g2[n*16 + ln]; }
    }

    float s[8] = {0,0,0,0,0,0,0,0}, sq[8] = {0,0,0,0,0,0,0,0};

    for (int g = blockIdx.x*4 + wv; g < NG; g += 4096) {
        const float nqx = nxyz[g*3+0], nqy = nxyz[g*3+1], nqz = nxyz[g*3+2];
        short8 a1[2][3];
        #pragma unroll
        for (int Mt = 0; Mt < 2; ++Mt) {
            int nb = idxw[g*32 + Mt*16 + ln];
            int row = (g >> 10)*NN + nb;
            const float* p = pts + row*64 + q8*8;
            float4 f0 = *(const float4*)p, f1 = *(const float4*)(p + 4);
            float4 f2 = *(const float4*)(p + 32), f3 = *(const float4*)(p + 36);
            UF t0, t1;
            t0.u.x = pk2f(f0.x, f0.y); t0.u.y = pk2f(f0.z, f0.w);
            t0.u.z = pk2f(f1.x, f1.y); t0.u.w = pk2f(f1.z, f1.w);
            a1[Mt][0] = t0.s;
            t1.u.x = pk2f(f2.x, f2.y); t1.u.y = pk2f(f2.z, f2.w);
            t1.u.z = pk2f(f3.x, f3.y); t1.u.w = pk2f(f3.z, f3.w);
            a1[Mt][1] = t1.s;
            UF x; x.u = make_uint4(0,0,0,0);
            if (q8 == 0) {
                float vx = xyz[row*3+0] - nqx, vy = xyz[row*3+1] - nqy, vz = xyz[row*3+2] - nqz;
                unsigned bx = __float_as_uint(vx), by = __float_as_uint(vy), bz = __float_as_uint(vz);
                float rx = vx - __uint_as_float(bx & 0xffff0000u);
                float ry = vy - __uint_as_float(by & 0xffff0000u);
                float rz = vz - __uint_as_float(bz & 0xffff0000u);
                x.u.x = pk2r(bx, by);
                x.u.y = pk2r(bz, rtneb(rx));
                x.u.z = pk2r(rtneb(ry), rtneb(rz));
            }
            a1[Mt][2] = x.s;
        }

        float4v acc1[2][4];
        #pragma unroll
        for (int Mt = 0; Mt < 2; ++Mt)
            #pragma unroll
            for (int Nt = 0; Nt < 4; ++Nt)
                acc1[Mt][Nt] = (float4v){b0v[Nt], b0v[Nt], b0v[Nt], b0v[Nt]};
        #pragma unroll
        for (int Ks = 0; Ks < 3; ++Ks)
            #pragma unroll
            for (int Nt = 0; Nt < 4; ++Nt) {
                short8 bf = ldw(w0f, (Nt*3 + Ks)*64 + l);
                #pragma unroll
                for (int Mt = 0; Mt < 2; ++Mt)
                    acc1[Mt][Nt] = __builtin_amdgcn_mfma_f32_16x16x32_bf16(
                        a1[Mt][Ks], bf, acc1[Mt][Nt], 0, 0, 0);
            }

        if constexpr (STAGE == 1) {
            #pragma unroll
            for (int Nt = 0; Nt < 4; ++Nt)
                #pragma unroll
                for (int Mt = 0; Mt < 2; ++Mt)
                    #pragma unroll
                    for (int r = 0; r < 4; ++r) {
                        float h = acc1[Mt][Nt][r];
                        s[Nt] += h; sq[Nt] += h*h;
                    }
        }

        if constexpr (STAGE >= 2) {
            #pragma unroll
            for (int Mt = 0; Mt < 2; ++Mt)
                #pragma unroll
                for (int Nt = 0; Nt < 4; ++Nt)
                    #pragma unroll
                    for (int r = 0; r < 4; ++r) {
                        float z = fmaxf(fmaf(acc1[Mt][Nt][r], sc1v[Nt], sf1v[Nt]), 0.f);
                        unsigned zu = __float_as_uint(z);
                        float rr = z - __uint_as_float(zu & 0xffff0000u);
                        *(unsigned*)&zw[(Mt*16 + q8*4 + r)*136 + 2*(Nt*16 + ln)] = pk2r(zu, rtneb(rr));
                    }
            LDS_SYNC();

            float4v acc2[2][4];
            #pragma unroll
            for (int Mt = 0; Mt < 2; ++Mt)
                #pragma unroll
                for (int Nt = 0; Nt < 4; ++Nt)
                    acc2[Mt][Nt] = (float4v){b1v[Nt], b1v[Nt], b1v[Nt], b1v[Nt]};
            #pragma unroll
            for (int Ks = 0; Ks < 4; ++Ks) {
                short8 a2[2];
                #pragma unroll
                for (int Mt = 0; Mt < 2; ++Mt)
                    a2[Mt] = *(const short8*)&zw[(Mt*16 + ln)*136 + Ks*32 + q8*8];
                #pragma unroll
                for (int Nt = 0; Nt < 4; ++Nt) {
                    short8 bf = ldw(w1f, (Nt*4 + Ks)*64 + l);
                    #pragma unroll
                    for (int Mt = 0; Mt < 2; ++Mt)
                        acc2[Mt][Nt] = __builtin_amdgcn_mfma_f32_16x16x32_bf16(
                            a2[Mt], bf, acc2[Mt][Nt], 0, 0, 0);
                }
            }

            if constexpr (STAGE == 2) {
                #pragma unroll
                for (int Nt = 0; Nt < 4; ++Nt)
                    #pragma unroll
                    for (int Mt = 0; Mt < 2; ++Mt)
                        #pragma unroll
                        for (int r = 0; r < 4; ++r) {
                            float h = acc2[Mt][Nt][r];
                            s[Nt] += h; sq[Nt] += h*h;
                        }
            }

            if constexpr (STAGE == 3) {
                LDS_SYNC();
                #pragma unroll
                for (int Mt = 0; Mt < 2; ++Mt)
                    #pragma unroll
                    for (int Nt = 0; Nt < 4; ++Nt)
                        #pragma unroll
                        for (int r = 0; r < 4; ++r) {
                            float z = fmaxf(fmaf(acc2[Mt][Nt][r], sc2v[Nt], sf2v[Nt]), 0.f);
                            unsigned zu = __float_as_uint(z);
                            float rr = z - __uint_as_float(zu & 0xffff0000u);
                            *(unsigned*)&zw[(Mt*16 + q8*4 + r)*136 + 2*(Nt*16 + ln)] = pk2r(zu, rtneb(rr));
                        }
                LDS_SYNC();

                float4v acc3[2][8];
                #pragma unroll
                for (int Mt = 0; Mt < 2; ++Mt)
                    #pragma unroll
                    for (int Nt = 0; Nt < 8; ++Nt)
                        acc3[Mt][Nt] = (float4v){b2v[Nt], b2v[Nt], b2v[Nt], b2v[Nt]};
                #pragma unroll
                for (int Ks = 0; Ks < 4; ++Ks) {
                    short8 a2[2];
                    #pragma unroll
                    for (int Mt = 0; Mt < 2; ++Mt)
                        a2[Mt] = *(const short8*)&zw[(Mt*16 + ln)*136 + Ks*32 + q8*8];
                    #pragma unroll
                    for (int Nt = 0; Nt < 8; ++Nt) {
                        short8 bf = ldw(w2f, (Nt*4 + Ks)*64 + l);
                        #pragma unroll
                        for (int Mt = 0; Mt < 2; ++Mt)
                            acc3[Mt][Nt] = __builtin_amdgcn_mfma_f32_16x16x32_bf16(
                                a2[Mt], bf, acc3[Mt][Nt], 0, 0, 0);
                    }
                }

                float mm[8];
                #pragma unroll
                for (int Nt = 0; Nt < 8; ++Nt) {
                    const bool pos = g2v[Nt] >= 0.f;
                    float m = acc3[0][Nt][0];
                    #pragma unroll
                    for (int Mt = 0; Mt < 2; ++Mt)
                        #pragma unroll
                        for (int r = 0; r < 4; ++r) {
                            float h = acc3[Mt][Nt][r];
                            s[Nt] += h; sq[Nt] += h*h;
                            if (!(Mt == 0 && r == 0))
                                m = pos ? fmaxf(m, h) : fminf(m, h);
                        }
                    float o = __shfl_xor(m, 16); m = pos ? fmaxf(m, o) : fminf(m, o);
                    o = __shfl_xor(m, 32);       m = pos ? fmaxf(m, o) : fminf(m, o);
                    mm[Nt] = m;
                }
                if (l < 16) {
                    #pragma unroll
                    for (int Nt = 0; Nt < 8; ++Nt)
                        out_pts[(long)g*128 + Nt*16 + l] = mm[Nt];
                }
            }
        }
    }

    constexpr int NT = (STAGE == 3) ? 8 : 4;
    constexpr int soff = (STAGE == 1) ? 0 : (STAGE == 2) ? 128 : 256;
    constexpr int qoff = (STAGE == 1) ? 64 : (STAGE == 2) ? 192 : 384;
    #pragma unroll
    for (int t = 0; t < NT; ++t) {
        float a = s[t], b = sq[t];
        a += __shfl_xor(a, 16); a += __shfl_xor(a, 32);
        b += __shfl_xor(b, 16); b += __shfl_xor(b, 32);
        if (l < 16) {
            atomicAdd(&sums[soff + t*16 + l], a);
            atomicAdd(&sums[qoff + t*16 + l], b);
        }
    }
}

// ---------------- finalize: mean/var -> BN scale/shift ----------------
__global__ void k_fin(const float* __restrict__ sums, const float* __restrict__ g,
                      const float* __restrict__ be, float* __restrict__ scl,
                      int sum_off, int sq_off, int sc_off, int sh_off, int C)
{
    int c = threadIdx.x;
    if (c < C) {
        float mean = sums[sum_off + c] * (1.0f / PP);
        float var  = sums[sq_off + c] * (1.0f / PP) - mean * mean;
        float s = g[c] * rsqrtf(var + EPSF);
        scl[sc_off + c] = s;
        scl[sh_off + c] = be[c] - mean * s;
    }
}

// ---------------- apply BN3+ReLU to the pooled pre-activations ----------------
__global__ void k_bnmax(float* __restrict__ op, const float* __restrict__ scl) {
    int i = blockIdx.x * 256 + threadIdx.x;
    int c = i & 127;
    float sc = scl[256 + c], sf = scl[384 + c];
    op[i] = fmaxf(fmaf(op[i], sc, sf), 0.f);
}

extern "C" void kernel_launch(void* const* d_in, const int* in_sizes, int n_in,
                              void* d_out, int out_size, void* d_ws, size_t ws_size,
                              hipStream_t stream) {
    const float* xyz = (const float*)d_in[0];
    const float* pts = (const float*)d_in[1];
    const int*   fps = (const int*)d_in[2];
    const float* w0  = (const float*)d_in[3];
    const float* b0  = (const float*)d_in[4];
    const float* g0  = (const float*)d_in[5];
    const float* be0 = (const float*)d_in[6];
    const float* w1  = (const float*)d_in[7];
    const float* b1  = (const float*)d_in[8];
    const float* g1  = (const float*)d_in[9];
    const float* be1 = (const float*)d_in[10];
    const float* w2  = (const float*)d_in[11];
    const float* b2  = (const float*)d_in[12];
    const float* g2  = (const float*)d_in[13];
    const float* be2 = (const float*)d_in[14];

    float* ws = (float*)d_ws;
    float* out_xyz = (float*)d_out;
    float* out_pts = (float*)d_out + NG * 3;

    k_prep<<<1, 256, 0, stream>>>(w0, w1, w2, ws);
    k_select<<<NG / QPB, 512, 0, stream>>>(xyz, fps, out_xyz, ws);

    if (ws_size >= WS_FAST_BYTES) {
        ushort* h1 = (ushort*)(ws + WS_H1);
        ushort* h2 = (ushort*)(ws + WS_H2);
        k_g1<<<1024, 256, 0, stream>>>(xyz, pts, b0, ws, h1);
        k_fin<<<1, 128, 0, stream>>>(ws + WS_SUMS, g0, be0, ws + WS_SCALE, 0, 64, 0, 64, 64);
        k_g2<<<1024, 256, 0, stream>>>(b1, ws, h1, h2);
        k_fin<<<1, 128, 0, stream>>>(ws + WS_SUMS, g1, be1, ws + WS_SCALE, 128, 192, 128, 192, 64);
        k_g3<<<1024, 256, 0, stream>>>(b2, g2, ws, h2, out_pts);
        k_fin<<<1, 128, 0, stream>>>(ws + WS_SUMS, g2, be2, ws + WS_SCALE, 256, 384, 256, 384, 128);
    } else {
        k_passF<1><<<1024, 256, 0, stream>>>(xyz, pts, b0, b1, b2, g2, ws, out_pts);
        k_fin<<<1, 128, 0, stream>>>(ws + WS_SUMS, g0, be0, ws + WS_SCALE, 0, 64, 0, 64, 64);
        k_passF<2><<<1024, 256, 0, stream>>>(xyz, pts, b0, b1, b2, g2, ws, out_pts);
        k_fin<<<1, 128, 0, stream>>>(ws + WS_SUMS, g1, be1, ws + WS_SCALE, 128, 192, 128, 192, 64);
        k_passF<3><<<1024, 256, 0, stream>>>(xyz, pts, b0, b1, b2, g2, ws, out_pts);
        k_fin<<<1, 128, 0, stream>>>(ws + WS_SUMS, g2, be2, ws + WS_SCALE, 256, 384, 256, 384, 128);
    }
    k_bnmax<<<NG * 128 / 256, 256, 0, stream>>>(out_pts, ws + WS_SCALE);
}

// Round 13
// 353.253 us; speedup vs baseline: 1.5641x; 1.5641x over previous
//
#include <hip/hip_runtime.h>
#include <hip/hip_bf16.h>

// All float tensors are fp32 (TRUE fp32 values — selection must use exact fp32;
// bf16-level VALUE error is only tolerable in the MLP). fps_idx int32.
// HARD CONSTRAINT (R5+R12 lessons): MFMA g-passes must stay at
// __launch_bounds__(256,2) — any tighter waves/EU floor spills the
// accumulator file to scratch (WRITE_SIZE blows up 27x).

typedef __attribute__((ext_vector_type(8))) short short8;
typedef __attribute__((ext_vector_type(4))) float float4v;

constexpr int BB = 16, NN = 4096, SS = 1024, DD = 64, KK = 32;
constexpr int PP = BB * SS * KK;            // 524288 grouped points
constexpr int NG = BB * SS;                 // 16384 query groups
constexpr float EPSF = 1e-5f;
constexpr int CAND_MAX = 640;               // per-wave kNN candidate cap
constexpr int QPB = 8;                      // queries (waves) per select block

// Workspace layout (float offsets).
constexpr int WS_IDX   = 0;                    // ushort[PP]
constexpr int WS_NXYZ  = PP / 2;               // float[NG*3]
constexpr int WS_W0PK  = WS_NXYZ + NG*3;       // ushort[6144]  W0' frag image (K=96: feat + xyz hi/lo)
constexpr int WS_W1PK  = WS_W0PK + 3072;       // ushort[4096]  W1' frag image (K=64, bf16-only)
constexpr int WS_W2PK  = WS_W1PK + 2048;       // ushort[8192]  W2' frag image (K=64, bf16-only)
constexpr int WS_W1PKD = WS_W2PK + 4096;       // ushort[8192]  W1 dup image (K=128 hi/lo, fallback)
constexpr int WS_W2PKD = WS_W1PKD + 4096;      // ushort[16384] W2 dup image (K=128 hi/lo, fallback)
constexpr int WS_SUMS  = WS_W2PKD + 8192;      // float[512]
constexpr int WS_SCALE = WS_SUMS + 512;        // float[512]
constexpr int WS_H1    = WS_SCALE + 512;       // ushort[PP*64] pre-BN H1 (bf16)
constexpr int WS_H2    = WS_H1 + PP*32;        // ushort[PP*64] pre-BN H2 (bf16)
constexpr int WS_END   = WS_H2 + PP*32;
constexpr size_t WS_FAST_BYTES = (size_t)WS_END * 4;

__device__ __forceinline__ unsigned rtne16(float x) {
    unsigned b = __float_as_uint(x);
    return (b + 0x7fffu + ((b >> 16) & 1u)) >> 16;
}
// bf16 RTNE bits left in [31:16]
__device__ __forceinline__ unsigned rtneb(float r) {
    unsigned b = __float_as_uint(r);
    return b + 0x7fffu + ((b >> 16) & 1u);
}
// pack: low16 = a[31:16], high16 = b[31:16]
__device__ __forceinline__ unsigned pk2r(unsigned a, unsigned b) {
    return __builtin_amdgcn_perm(a, b, 0x03020706u);
}
__device__ __forceinline__ unsigned pk2f(float a, float b) {
    return pk2r(__float_as_uint(a), __float_as_uint(b));
}
// unpack bf16 pair, apply BN+ReLU per element, repack to bf16 pair
__device__ __forceinline__ unsigned bnpack(unsigned u, float sce, float sfe,
                                           float sco, float sfo) {
    float fe = __uint_as_float(u << 16);
    float fo = __uint_as_float(u & 0xffff0000u);
    float ze = fmaxf(fmaf(fe, sce, sfe), 0.f);
    float zo = fmaxf(fmaf(fo, sco, sfo), 0.f);
    return pk2r(rtneb(ze), rtneb(zo));
}

union UF { uint4 u; short8 s; };
__device__ __forceinline__ short8 ldw(const uint4* __restrict__ p, int idx) {
    UF u; u.u = p[idx]; return u.s;
}

#define LDS_SYNC() asm volatile("s_waitcnt lgkmcnt(0)" ::: "memory")

// ---------------- prep: frag-major bf16 weight images + zero stats ----------------
__global__ void k_prep(const float* __restrict__ w0, const float* __restrict__ w1,
                       const float* __restrict__ w2, float* __restrict__ ws) {
    const int t = threadIdx.x;
    ushort* w0pk = (ushort*)(ws + WS_W0PK);
    for (int i = t; i < 6144; i += 256) {        // [Nt(4)][Ks(3)][lane(64)][j(8)]
        int j = i & 7, l = (i >> 3) & 63, Ks = (i >> 9) % 3, Nt = i / 1536;
        int o = Nt*16 + (l & 15);
        int k = Ks*32 + (l >> 4)*8 + j;
        float v = 0.f;
        if (k < 64)      v = w0[o*67 + 3 + k];
        else if (k < 67) v = w0[o*67 + (k - 64)];     // xyz hi
        else if (k < 70) v = w0[o*67 + (k - 67)];     // xyz lo (same weights)
        w0pk[i] = (ushort)rtne16(v);
    }
    ushort* w1pk = (ushort*)(ws + WS_W1PK);
    for (int i = t; i < 4096; i += 256) {        // [Nt(4)][Ks(2)][lane][j], K=64
        int j = i & 7, l = (i >> 3) & 63, Ks = (i >> 9) & 1, Nt = i >> 10;
        int o = Nt*16 + (l & 15);
        int k = Ks*32 + (l >> 4)*8 + j;
        w1pk[i] = (ushort)rtne16(w1[o*64 + k]);
    }
    ushort* w2pk = (ushort*)(ws + WS_W2PK);
    for (int i = t; i < 8192; i += 256) {        // [Nt(8)][Ks(2)][lane][j], K=64
        int j = i & 7, l = (i >> 3) & 63, Ks = (i >> 9) & 1, Nt = i >> 10;
        int o = Nt*16 + (l & 15);
        int k = Ks*32 + (l >> 4)*8 + j;
        w2pk[i] = (ushort)rtne16(w2[o*64 + k]);
    }
    // fallback dup images (K=128 hi/lo interleaved)
    ushort* w1pd = (ushort*)(ws + WS_W1PKD);
    for (int i = t; i < 8192; i += 256) {        // [Nt(4)][Ks(4)][lane][j]
        int j = i & 7, l = (i >> 3) & 63, Ks = (i >> 9) & 3, Nt = i >> 11;
        int o = Nt*16 + (l & 15);
        int c = (Ks*32 + (l >> 4)*8 + j) >> 1;
        w1pd[i] = (ushort)rtne16(w1[o*64 + c]);
    }
    ushort* w2pd = (ushort*)(ws + WS_W2PKD);
    for (int i = t; i < 16384; i += 256) {       // [Nt(8)][Ks(4)][lane][j]
        int j = i & 7, l = (i >> 3) & 63, Ks = (i >> 9) & 3, Nt = i >> 11;
        int o = Nt*16 + (l & 15);
        int c = (Ks*32 + (l >> 4)*8 + j) >> 1;
        w2pd[i] = (ushort)rtne16(w2[o*64 + c]);
    }
    for (int i = t; i < 512; i += 256) ws[WS_SUMS + i] = 0.f;
}

// ---------------- select: exact top-32 nearest neighbors per query ----------------
// 8 waves (512 threads) share a float4 tile (x,y,z,|p|^2) — |p|^2 precomputed
// at tile load with the exact reference rounding chain, so keys are bit-identical
// to the proven R7/R8 path but each keyAt is 1 ds_read_b128 + 8 VALU.
// Phase A stores the 64 keys/lane in VGPRs (single eval per key); candidates are
// ballot-compacted as INDICES only (10 KB LDS); fast path recomputes <=10
// keys/lane from the tile, binary-searches T, and emits with exact top_k ties.
__global__ __launch_bounds__(512, 4) void k_select(
    const float* __restrict__ xyz, const int* __restrict__ fps,
    float* __restrict__ out_xyz, float* __restrict__ ws)
{
    __shared__ float4 sp[NN];                   // 64 KB exact fp32 x,y,z,|p|^2
    __shared__ ushort cbi[QPB][CAND_MAX];       // 10 KB candidate indices
    const int tid = threadIdx.x;
    const int qb = blockIdx.x * QPB;
    const int b  = qb >> 10;
    const float* __restrict__ xb = xyz + (long)b * NN * 3;
    for (int i = tid; i < NN; i += 512) {
        float x = xb[i*3 + 0], y = xb[i*3 + 1], z = xb[i*3 + 2];
        float pw = __fadd_rn(__fadd_rn(__fmul_rn(x,x), __fmul_rn(y,y)), __fmul_rn(z,z));
        sp[i] = make_float4(x, y, z, pw);
    }
    __syncthreads();

    const int wave = tid >> 6, lane = tid & 63;
    const int q = qb + wave;
    const int nq = fps[q];
    const float4 qp = sp[nq];                   // broadcast read (free)
    const float qx = qp.x, qy = qp.y, qz = qp.z, qw = qp.w;

    float* nxyz = ws + WS_NXYZ;
    unsigned short* idx_ws = (unsigned short*)ws;
    if (lane < 3) {
        float v = (lane == 0) ? qx : ((lane == 1) ? qy : qz);
        out_xyz[q*3 + lane] = v;
        nxyz[q*3 + lane] = v;
    }

    // key for tile point n: exact fp32, deterministic op sequence
    auto keyAt = [&](int n) -> unsigned {
        float4 pp = sp[n];
        float dot = fmaf(qx, pp.x, 0.f);
        dot = fmaf(qy, pp.y, dot);
        dot = fmaf(qz, pp.z, dot);
        float d = __fadd_rn(__fadd_rn(__fmul_rn(-2.0f, dot), qw), pp.w);
        unsigned u = __float_as_uint(d);
        return u ^ (unsigned)(((int)u >> 31) | 0x80000000);
    };

    // phase A: 64 keys/lane, stored in VGPRs (one eval per key)
    unsigned key[64];
    unsigned lmin = 0xFFFFFFFFu, lmax = 0u;
    #pragma unroll
    for (int i = 0; i < 64; ++i) {
        unsigned k = keyAt(i*64 + lane);
        key[i] = k;
        lmin = min(lmin, k); lmax = max(lmax, k);
    }
    unsigned gmin = lmin, gmax = lmax, Bv = lmin;
    #pragma unroll
    for (int off = 32; off > 0; off >>= 1) {
        gmin = min(gmin, (unsigned)__shfl_xor((int)gmin, off));
        gmax = max(gmax, (unsigned)__shfl_xor((int)gmax, off));
        Bv   = max(Bv,   (unsigned)__shfl_xor((int)Bv,   off));
    }
    // Bv = max of lane minima >= 64th smallest key >= T

    const unsigned long long lmask = (1ull << lane) - 1ull;
    ushort* ciw = cbi[wave];

    // compaction: candidate indices (<= Bv), ascending global index
    int cnt = 0;
    #pragma unroll
    for (int i = 0; i < 64; ++i) {
        bool pr = key[i] <= Bv;
        unsigned long long m = __ballot(pr);
        int pos = cnt + (int)__popcll(m & lmask);
        if (pr && pos < CAND_MAX) ciw[pos] = (ushort)(i*64 + lane);
        cnt += (int)__popcll(m);
    }
    const int base = q * KK;

    if (cnt <= CAND_MAX) {
        LDS_SYNC();
        // candidates into regs (static 10 slots, keys recomputed from tile)
        unsigned cr[10]; ushort ir[10];
        #pragma unroll
        for (int r = 0; r < 10; ++r) {
            int j = r*64 + lane;
            bool v = j < cnt;
            ushort idx = v ? ciw[j] : (ushort)0;
            ir[r] = idx;
            cr[r] = v ? keyAt(idx) : 0xFFFFFFFFu;
        }
        // binary search smallest T in [gmin, Bv] with count(<=T) >= 32
        unsigned lo = gmin, hi = Bv;
        while (lo < hi) {
            unsigned mid = lo + ((hi - lo) >> 1);
            int c = 0;
            #pragma unroll
            for (int r = 0; r < 10; ++r)
                c += (int)__popcll(__ballot(cr[r] <= mid));
            if (c >= 32) hi = mid; else lo = mid + 1;
        }
        const unsigned T = lo;

        int c2 = 0;
        #pragma unroll
        for (int r = 0; r < 10; ++r) {           // strictly closer (count < 32)
            bool pr = cr[r] < T;
            unsigned long long m = __ballot(pr);
            if (pr) idx_ws[base + c2 + (int)__popcll(m & lmask)] = ir[r];
            c2 += (int)__popcll(m);
        }
        #pragma unroll
        for (int r = 0; r < 10; ++r) {           // ties, smallest index first
            bool pr = cr[r] == T;
            unsigned long long m = __ballot(pr);
            int pos = c2 + (int)__popcll(m & lmask);
            if (pr && pos < KK) idx_ws[base + pos] = ir[r];
            c2 += (int)__popcll(m);
        }
    } else {
        // ultra-rare fallback: full-range in-register search (keys stored)
        unsigned lo = gmin, hi = gmax;
        while (lo < hi) {
            unsigned mid = lo + ((hi - lo) >> 1);
            int c = 0;
            #pragma unroll
            for (int i = 0; i < 64; ++i)
                c += (int)__popcll(__ballot(key[i] <= mid));
            if (c >= 32) hi = mid; else lo = mid + 1;
        }
        const unsigned T = lo;
        int c2 = 0;
        #pragma unroll
        for (int i = 0; i < 64; ++i) {
            bool pr = key[i] < T;
            unsigned long long m = __ballot(pr);
            if (pr) idx_ws[base + c2 + (int)__popcll(m & lmask)] = (ushort)(i*64 + lane);
            c2 += (int)__popcll(m);
        }
        #pragma unroll
        for (int i = 0; i < 64; ++i) {
            bool pr = key[i] == T;
            unsigned long long m = __ballot(pr);
            int pos = c2 + (int)__popcll(m & lmask);
            if (pr && pos < KK) idx_ws[base + pos] = (ushort)(i*64 + lane);
            c2 += (int)__popcll(m);
        }
    }
}

// ================= fast path: materialized pre-BN activations =================
// H layout: ushort bf16 H[p][c], p = grouped point (g*32 + m). A-frag reads and
// C-writes are coalesced; no LDS roundtrip, no recompute.
// launch_bounds MUST stay (256,2) — see header note.

// ---- pass A: gather + GEMM1 -> H1 + stats1 ----
__global__ __launch_bounds__(256, 2) void k_g1(
    const float* __restrict__ xyz, const float* __restrict__ pts,
    const float* __restrict__ b0, float* __restrict__ ws,
    ushort* __restrict__ h1)
{
    __shared__ float rbuf[4][128];
    const int tid = threadIdx.x;
    const int wv = tid >> 6, l = tid & 63, ln = l & 15, q8 = l >> 4;

    const ushort* idxw = (const ushort*)ws;
    const float* nxyz = ws + WS_NXYZ;
    float* sums = ws + WS_SUMS;
    const uint4* w0f = (const uint4*)(ws + WS_W0PK);

    short8 w0r[12];
    #pragma unroll
    for (int t = 0; t < 12; ++t) w0r[t] = ldw(w0f, t*64 + l);
    float b0v[4];
    #pragma unroll
    for (int n = 0; n < 4; ++n) b0v[n] = b0[n*16 + ln];

    float s[4] = {0,0,0,0}, sq[4] = {0,0,0,0};
    const int gbase = blockIdx.x*4 + wv;

    for (int it = 0; it < 4; ++it) {
        const int g = gbase + it*4096;
        const float nqx = nxyz[g*3+0], nqy = nxyz[g*3+1], nqz = nxyz[g*3+2];

        short8 a1[2][3];
        #pragma unroll
        for (int Mt = 0; Mt < 2; ++Mt) {
            int nb = idxw[g*32 + Mt*16 + ln];
            int row = (g >> 10)*NN + nb;
            const float* p = pts + row*64 + q8*8;
            float4 f0 = *(const float4*)p;
            float4 f1 = *(const float4*)(p + 4);
            float4 f2 = *(const float4*)(p + 32);
            float4 f3 = *(const float4*)(p + 36);
            UF t0, t1;
            t0.u.x = pk2f(f0.x, f0.y); t0.u.y = pk2f(f0.z, f0.w);
            t0.u.z = pk2f(f1.x, f1.y); t0.u.w = pk2f(f1.z, f1.w);
            a1[Mt][0] = t0.s;
            t1.u.x = pk2f(f2.x, f2.y); t1.u.y = pk2f(f2.z, f2.w);
            t1.u.z = pk2f(f3.x, f3.y); t1.u.w = pk2f(f3.z, f3.w);
            a1[Mt][1] = t1.s;
            UF x; x.u = make_uint4(0,0,0,0);
            if (q8 == 0) {
                float vx = xyz[row*3+0] - nqx;
                float vy = xyz[row*3+1] - nqy;
                float vz = xyz[row*3+2] - nqz;
                unsigned bx = __float_as_uint(vx), by = __float_as_uint(vy), bz = __float_as_uint(vz);
                float rx = vx - __uint_as_float(bx & 0xffff0000u);
                float ry = vy - __uint_as_float(by & 0xffff0000u);
                float rz = vz - __uint_as_float(bz & 0xffff0000u);
                x.u.x = pk2r(bx, by);
                x.u.y = pk2r(bz, rtneb(rx));
                x.u.z = pk2r(rtneb(ry), rtneb(rz));
            }
            a1[Mt][2] = x.s;
        }

        float4v acc[2][4];
        #pragma unroll
        for (int Mt = 0; Mt < 2; ++Mt)
            #pragma unroll
            for (int Nt = 0; Nt < 4; ++Nt)
                acc[Mt][Nt] = (float4v){b0v[Nt], b0v[Nt], b0v[Nt], b0v[Nt]};
        #pragma unroll
        for (int Ks = 0; Ks < 3; ++Ks)
            #pragma unroll
            for (int Nt = 0; Nt < 4; ++Nt)
                #pragma unroll
                for (int Mt = 0; Mt < 2; ++Mt)
                    acc[Mt][Nt] = __builtin_amdgcn_mfma_f32_16x16x32_bf16(
                        a1[Mt][Ks], w0r[Nt*3 + Ks], acc[Mt][Nt], 0, 0, 0);

        #pragma unroll
        for (int Mt = 0; Mt < 2; ++Mt)
            #pragma unroll
            for (int Nt = 0; Nt < 4; ++Nt)
                #pragma unroll
                for (int r = 0; r < 4; ++r) {
                    float h = acc[Mt][Nt][r];
                    s[Nt] += h; sq[Nt] += h*h;
                    h1[(g*32 + Mt*16 + q8*4 + r)*64 + Nt*16 + ln] = (ushort)rtne16(h);
                }
    }

    #pragma unroll
    for (int t = 0; t < 4; ++t) {
        float a = s[t], b = sq[t];
        a += __shfl_xor(a, 16); a += __shfl_xor(a, 32);
        b += __shfl_xor(b, 16); b += __shfl_xor(b, 32);
        if (l < 16) { rbuf[wv][t*16 + l] = a; rbuf[wv][64 + t*16 + l] = b; }
    }
    __syncthreads();
    if (wv == 0 && l < 16) {
        #pragma unroll
        for (int t = 0; t < 4; ++t) {
            float a = rbuf[0][t*16+l] + rbuf[1][t*16+l] + rbuf[2][t*16+l] + rbuf[3][t*16+l];
            float b = rbuf[0][64+t*16+l] + rbuf[1][64+t*16+l] + rbuf[2][64+t*16+l] + rbuf[3][64+t*16+l];
            atomicAdd(&sums[t*16 + l], a);
            atomicAdd(&sums[64 + t*16 + l], b);
        }
    }
}

// ---- pass B: H1 -> BN1+ReLU -> GEMM2 -> H2 + stats2 ----
__global__ __launch_bounds__(256, 2) void k_g2(
    const float* __restrict__ b1, float* __restrict__ ws,
    const ushort* __restrict__ h1, ushort* __restrict__ h2)
{
    __shared__ float rbuf[4][128];
    const int tid = threadIdx.x;
    const int wv = tid >> 6, l = tid & 63, ln = l & 15, q8 = l >> 4;

    const float* scl = ws + WS_SCALE;
    float* sums = ws + WS_SUMS;
    const uint4* w1f = (const uint4*)(ws + WS_W1PK);

    float b1v[4];
    #pragma unroll
    for (int n = 0; n < 4; ++n) b1v[n] = b1[n*16 + ln];
    float4 sc[2][2], sf[2][2];
    #pragma unroll
    for (int Ks = 0; Ks < 2; ++Ks) {
        sc[Ks][0] = *(const float4*)&scl[Ks*32 + q8*8];
        sc[Ks][1] = *(const float4*)&scl[Ks*32 + q8*8 + 4];
        sf[Ks][0] = *(const float4*)&scl[64 + Ks*32 + q8*8];
        sf[Ks][1] = *(const float4*)&scl[64 + Ks*32 + q8*8 + 4];
    }

    float s[4] = {0,0,0,0}, sq[4] = {0,0,0,0};
    const int gbase = blockIdx.x*4 + wv;

    for (int it = 0; it < 4; ++it) {
        const int g = gbase + it*4096;

        short8 a[2][2];
        #pragma unroll
        for (int Mt = 0; Mt < 2; ++Mt)
            #pragma unroll
            for (int Ks = 0; Ks < 2; ++Ks) {
                uint4 hv = *(const uint4*)&h1[(g*32 + Mt*16 + ln)*64 + Ks*32 + q8*8];
                UF t;
                t.u.x = bnpack(hv.x, sc[Ks][0].x, sf[Ks][0].x, sc[Ks][0].y, sf[Ks][0].y);
                t.u.y = bnpack(hv.y, sc[Ks][0].z, sf[Ks][0].z, sc[Ks][0].w, sf[Ks][0].w);
                t.u.z = bnpack(hv.z, sc[Ks][1].x, sf[Ks][1].x, sc[Ks][1].y, sf[Ks][1].y);
                t.u.w = bnpack(hv.w, sc[Ks][1].z, sf[Ks][1].z, sc[Ks][1].w, sf[Ks][1].w);
                a[Mt][Ks] = t.s;
            }

        float4v acc[2][4];
        #pragma unroll
        for (int Mt = 0; Mt < 2; ++Mt)
            #pragma unroll
            for (int Nt = 0; Nt < 4; ++Nt)
                acc[Mt][Nt] = (float4v){b1v[Nt], b1v[Nt], b1v[Nt], b1v[Nt]};
        #pragma unroll
        for (int Ks = 0; Ks < 2; ++Ks)
            #pragma unroll
            for (int Nt = 0; Nt < 4; ++Nt) {
                short8 bf = ldw(w1f, (Nt*2 + Ks)*64 + l);
                #pragma unroll
                for (int Mt = 0; Mt < 2; ++Mt)
                    acc[Mt][Nt] = __builtin_amdgcn_mfma_f32_16x16x32_bf16(
                        a[Mt][Ks], bf, acc[Mt][Nt], 0, 0, 0);
            }

        #pragma unroll
        for (int Mt = 0; Mt < 2; ++Mt)
            #pragma unroll
            for (int Nt = 0; Nt < 4; ++Nt)
                #pragma unroll
                for (int r = 0; r < 4; ++r) {
                    float h = acc[Mt][Nt][r];
                    s[Nt] += h; sq[Nt] += h*h;
                    h2[(g*32 + Mt*16 + q8*4 + r)*64 + Nt*16 + ln] = (ushort)rtne16(h);
                }
    }

    #pragma unroll
    for (int t = 0; t < 4; ++t) {
        float a = s[t], b = sq[t];
        a += __shfl_xor(a, 16); a += __shfl_xor(a, 32);
        b += __shfl_xor(b, 16); b += __shfl_xor(b, 32);
        if (l < 16) { rbuf[wv][t*16 + l] = a; rbuf[wv][64 + t*16 + l] = b; }
    }
    __syncthreads();
    if (wv == 0 && l < 16) {
        #pragma unroll
        for (int t = 0; t < 4; ++t) {
            float a = rbuf[0][t*16+l] + rbuf[1][t*16+l] + rbuf[2][t*16+l] + rbuf[3][t*16+l];
            float b = rbuf[0][64+t*16+l] + rbuf[1][64+t*16+l] + rbuf[2][64+t*16+l] + rbuf[3][64+t*16+l];
            atomicAdd(&sums[128 + t*16 + l], a);
            atomicAdd(&sums[192 + t*16 + l], b);
        }
    }
}

// ---- pass C: H2 -> BN2+ReLU -> GEMM3 -> stats3 + pre-BN pool -> out ----
__global__ __launch_bounds__(256, 2) void k_g3(
    const float* __restrict__ b2, const float* __restrict__ g2,
    float* __restrict__ ws, const ushort* __restrict__ h2,
    float* __restrict__ out_pts)
{
    __shared__ float rbuf[4][256];
    const int tid = threadIdx.x;
    const int wv = tid >> 6, l = tid & 63, ln = l & 15, q8 = l >> 4;

    const float* scl = ws + WS_SCALE;
    float* sums = ws + WS_SUMS;
    const uint4* w2f = (const uint4*)(ws + WS_W2PK);

    float b2v[8], g2v[8];
    #pragma unroll
    for (int n = 0; n < 8; ++n) { b2v[n] = b2[n*16 + ln]; g2v[n] = g2[n*16 + ln]; }
    float4 sc[2][2], sf[2][2];
    #pragma unroll
    for (int Ks = 0; Ks < 2; ++Ks) {
        sc[Ks][0] = *(const float4*)&scl[128 + Ks*32 + q8*8];
        sc[Ks][1] = *(const float4*)&scl[128 + Ks*32 + q8*8 + 4];
        sf[Ks][0] = *(const float4*)&scl[192 + Ks*32 + q8*8];
        sf[Ks][1] = *(const float4*)&scl[192 + Ks*32 + q8*8 + 4];
    }

    float s[8] = {0,0,0,0,0,0,0,0}, sq[8] = {0,0,0,0,0,0,0,0};
    const int gbase = blockIdx.x*4 + wv;

    for (int it = 0; it < 4; ++it) {
        const int g = gbase + it*4096;

        short8 a[2][2];
        #pragma unroll
        for (int Mt = 0; Mt < 2; ++Mt)
            #pragma unroll
            for (int Ks = 0; Ks < 2; ++Ks) {
                uint4 hv = *(const uint4*)&h2[(g*32 + Mt*16 + ln)*64 + Ks*32 + q8*8];
                UF t;
                t.u.x = bnpack(hv.x, sc[Ks][0].x, sf[Ks][0].x, sc[Ks][0].y, sf[Ks][0].y);
                t.u.y = bnpack(hv.y, sc[Ks][0].z, sf[Ks][0].z, sc[Ks][0].w, sf[Ks][0].w);
                t.u.z = bnpack(hv.z, sc[Ks][1].x, sf[Ks][1].x, sc[Ks][1].y, sf[Ks][1].y);
                t.u.w = bnpack(hv.w, sc[Ks][1].z, sf[Ks][1].z, sc[Ks][1].w, sf[Ks][1].w);
                a[Mt][Ks] = t.s;
            }

        float4v acc[2][8];
        #pragma unroll
        for (int Mt = 0; Mt < 2; ++Mt)
            #pragma unroll
            for (int Nt = 0; Nt < 8; ++Nt)
                acc[Mt][Nt] = (float4v){b2v[Nt], b2v[Nt], b2v[Nt], b2v[Nt]};
        #pragma unroll
        for (int Ks = 0; Ks < 2; ++Ks)
            #pragma unroll
            for (int Nt = 0; Nt < 8; ++Nt) {
                short8 bf = ldw(w2f, (Nt*2 + Ks)*64 + l);
                #pragma unroll
                for (int Mt = 0; Mt < 2; ++Mt)
                    acc[Mt][Nt] = __builtin_amdgcn_mfma_f32_16x16x32_bf16(
                        a[Mt][Ks], bf, acc[Mt][Nt], 0, 0, 0);
            }

        float mm[8];
        #pragma unroll
        for (int Nt = 0; Nt < 8; ++Nt) {
            const bool pos = g2v[Nt] >= 0.f;
            float m = acc[0][Nt][0];
            #pragma unroll
            for (int Mt = 0; Mt < 2; ++Mt)
                #pragma unroll
                for (int r = 0; r < 4; ++r) {
                    float h = acc[Mt][Nt][r];
                    s[Nt] += h; sq[Nt] += h*h;
                    if (!(Mt == 0 && r == 0))
                        m = pos ? fmaxf(m, h) : fminf(m, h);
                }
            float o = __shfl_xor(m, 16); m = pos ? fmaxf(m, o) : fminf(m, o);
            o = __shfl_xor(m, 32);       m = pos ? fmaxf(m, o) : fminf(m, o);
            mm[Nt] = m;
        }
        if (l < 16) {
            #pragma unroll
            for (int Nt = 0; Nt < 8; ++Nt)
                out_pts[(long)g*128 + Nt*16 + l] = mm[Nt];
        }
    }

    #pragma unroll
    for (int t = 0; t < 8; ++t) {
        float a = s[t], b = sq[t];
        a += __shfl_xor(a, 16); a += __shfl_xor(a, 32);
        b += __shfl_xor(b, 16); b += __shfl_xor(b, 32);
        if (l < 16) { rbuf[wv][t*16 + l] = a; rbuf[wv][128 + t*16 + l] = b; }
    }
    __syncthreads();
    if (wv == 0 && l < 16) {
        #pragma unroll
        for (int t = 0; t < 8; ++t) {
            float a = rbuf[0][t*16+l] + rbuf[1][t*16+l] + rbuf[2][t*16+l] + rbuf[3][t*16+l];
            float b = rbuf[0][128+t*16+l] + rbuf[1][128+t*16+l] + rbuf[2][128+t*16+l] + rbuf[3][128+t*16+l];
            atomicAdd(&sums[256 + t*16 + l], a);
            atomicAdd(&sums[384 + t*16 + l], b);
        }
    }
}

// ================= fallback path (small ws): recompute, R4-style =================
template<int STAGE>
__global__ __launch_bounds__(256, 2) void k_passF(
    const float* __restrict__ xyz, const float* __restrict__ pts,
    const float* __restrict__ b0, const float* __restrict__ b1,
    const float* __restrict__ b2, const float* __restrict__ g2,
    float* __restrict__ ws, float* __restrict__ out_pts)
{
    __shared__ __align__(16) ushort zb[(STAGE >= 2) ? 4*32*136 : 8];
    const int tid = threadIdx.x;
    const int wv = tid >> 6, l = tid & 63, ln = l & 15, q8 = l >> 4;
    ushort* zw = &zb[(STAGE >= 2) ? wv*32*136 : 0];

    const ushort* idxw = (const ushort*)ws;
    const float* nxyz = ws + WS_NXYZ;
    const float* scl  = ws + WS_SCALE;
    float*       sums = ws + WS_SUMS;
    const uint4* w0f = (const uint4*)(ws + WS_W0PK);
    const uint4* w1f = (const uint4*)(ws + WS_W1PKD);
    const uint4* w2f = (const uint4*)(ws + WS_W2PKD);

    float b0v[4];
    #pragma unroll
    for (int n = 0; n < 4; ++n) b0v[n] = b0[n*16 + ln];
    float sc1v[4], sf1v[4], b1v[4];
    if constexpr (STAGE >= 2) {
        #pragma unroll
        for (int n = 0; n < 4; ++n) {
            sc1v[n] = scl[n*16 + ln]; sf1v[n] = scl[64 + n*16 + ln];
            b1v[n] = b1[n*16 + ln];
        }
    }
    float sc2v[4], sf2v[4], b2v[8], g2v[8];
    if constexpr (STAGE >= 3) {
        #pragma unroll
        for (int n = 0; n < 4; ++n) {
            sc2v[n] = scl[128 + n*16 + ln]; sf2v[n] = scl[192 + n*16 + ln];
        }
        #pragma unroll
        for (int n = 0; n < 8; ++n) { b2v[n] = b2[n*16 + ln]; g2v[n] = g2[n*16 + ln]; }
    }

    float s[8] = {0,0,0,0,0,0,0,0}, sq[8] = {0,0,0,0,0,0,0,0};

    for (int g = blockIdx.x*4 + wv; g < NG; g += 4096) {
        const float nqx = nxyz[g*3+0], nqy = nxyz[g*3+1], nqz = nxyz[g*3+2];
        short8 a1[2][3];
        #pragma unroll
        for (int Mt = 0; Mt < 2; ++Mt) {
            int nb = idxw[g*32 + Mt*16 + ln];
            int row = (g >> 10)*NN + nb;
            const float* p = pts + row*64 + q8*8;
            float4 f0 = *(const float4*)p, f1 = *(const float4*)(p + 4);
            float4 f2 = *(const float4*)(p + 32), f3 = *(const float4*)(p + 36);
            UF t0, t1;
            t0.u.x = pk2f(f0.x, f0.y); t0.u.y = pk2f(f0.z, f0.w);
            t0.u.z = pk2f(f1.x, f1.y); t0.u.w = pk2f(f1.z, f1.w);
            a1[Mt][0] = t0.s;
            t1.u.x = pk2f(f2.x, f2.y); t1.u.y = pk2f(f2.z, f2.w);
            t1.u.z = pk2f(f3.x, f3.y); t1.u.w = pk2f(f3.z, f3.w);
            a1[Mt][1] = t1.s;
            UF x; x.u = make_uint4(0,0,0,0);
            if (q8 == 0) {
                float vx = xyz[row*3+0] - nqx, vy = xyz[row*3+1] - nqy, vz = xyz[row*3+2] - nqz;
                unsigned bx = __float_as_uint(vx), by = __float_as_uint(vy), bz = __float_as_uint(vz);
                float rx = vx - __uint_as_float(bx & 0xffff0000u);
                float ry = vy - __uint_as_float(by & 0xffff0000u);
                float rz = vz - __uint_as_float(bz & 0xffff0000u);
                x.u.x = pk2r(bx, by);
                x.u.y = pk2r(bz, rtneb(rx));
                x.u.z = pk2r(rtneb(ry), rtneb(rz));
            }
            a1[Mt][2] = x.s;
        }

        float4v acc1[2][4];
        #pragma unroll
        for (int Mt = 0; Mt < 2; ++Mt)
            #pragma unroll
            for (int Nt = 0; Nt < 4; ++Nt)
                acc1[Mt][Nt] = (float4v){b0v[Nt], b0v[Nt], b0v[Nt], b0v[Nt]};
        #pragma unroll
        for (int Ks = 0; Ks < 3; ++Ks)
            #pragma unroll
            for (int Nt = 0; Nt < 4; ++Nt) {
                short8 bf = ldw(w0f, (Nt*3 + Ks)*64 + l);
                #pragma unroll
                for (int Mt = 0; Mt < 2; ++Mt)
                    acc1[Mt][Nt] = __builtin_amdgcn_mfma_f32_16x16x32_bf16(
                        a1[Mt][Ks], bf, acc1[Mt][Nt], 0, 0, 0);
            }

        if constexpr (STAGE == 1) {
            #pragma unroll
            for (int Nt = 0; Nt < 4; ++Nt)
                #pragma unroll
                for (int Mt = 0; Mt < 2; ++Mt)
                    #pragma unroll
                    for (int r = 0; r < 4; ++r) {
                        float h = acc1[Mt][Nt][r];
                        s[Nt] += h; sq[Nt] += h*h;
                    }
        }

        if constexpr (STAGE >= 2) {
            #pragma unroll
            for (int Mt = 0; Mt < 2; ++Mt)
                #pragma unroll
                for (int Nt = 0; Nt < 4; ++Nt)
                    #pragma unroll
                    for (int r = 0; r < 4; ++r) {
                        float z = fmaxf(fmaf(acc1[Mt][Nt][r], sc1v[Nt], sf1v[Nt]), 0.f);
                        unsigned zu = __float_as_uint(z);
                        float rr = z - __uint_as_float(zu & 0xffff0000u);
                        *(unsigned*)&zw[(Mt*16 + q8*4 + r)*136 + 2*(Nt*16 + ln)] = pk2r(zu, rtneb(rr));
                    }
            LDS_SYNC();

            float4v acc2[2][4];
            #pragma unroll
            for (int Mt = 0; Mt < 2; ++Mt)
                #pragma unroll
                for (int Nt = 0; Nt < 4; ++Nt)
                    acc2[Mt][Nt] = (float4v){b1v[Nt], b1v[Nt], b1v[Nt], b1v[Nt]};
            #pragma unroll
            for (int Ks = 0; Ks < 4; ++Ks) {
                short8 a2[2];
                #pragma unroll
                for (int Mt = 0; Mt < 2; ++Mt)
                    a2[Mt] = *(const short8*)&zw[(Mt*16 + ln)*136 + Ks*32 + q8*8];
                #pragma unroll
                for (int Nt = 0; Nt < 4; ++Nt) {
                    short8 bf = ldw(w1f, (Nt*4 + Ks)*64 + l);
                    #pragma unroll
                    for (int Mt = 0; Mt < 2; ++Mt)
                        acc2[Mt][Nt] = __builtin_amdgcn_mfma_f32_16x16x32_bf16(
                            a2[Mt], bf, acc2[Mt][Nt], 0, 0, 0);
                }
            }

            if constexpr (STAGE == 2) {
                #pragma unroll
                for (int Nt = 0; Nt < 4; ++Nt)
                    #pragma unroll
                    for (int Mt = 0; Mt < 2; ++Mt)
                        #pragma unroll
                        for (int r = 0; r < 4; ++r) {
                            float h = acc2[Mt][Nt][r];
                            s[Nt] += h; sq[Nt] += h*h;
                        }
            }

            if constexpr (STAGE == 3) {
                LDS_SYNC();
                #pragma unroll
                for (int Mt = 0; Mt < 2; ++Mt)
                    #pragma unroll
                    for (int Nt = 0; Nt < 4; ++Nt)
                        #pragma unroll
                        for (int r = 0; r < 4; ++r) {
                            float z = fmaxf(fmaf(acc2[Mt][Nt][r], sc2v[Nt], sf2v[Nt]), 0.f);
                            unsigned zu = __float_as_uint(z);
                            float rr = z - __uint_as_float(zu & 0xffff0000u);
                            *(unsigned*)&zw[(Mt*16 + q8*4 + r)*136 + 2*(Nt*16 + ln)] = pk2r(zu, rtneb(rr));
                        }
                LDS_SYNC();

                float4v acc3[2][8];
                #pragma unroll
                for (int Mt = 0; Mt < 2; ++Mt)
                    #pragma unroll
                    for (int Nt = 0; Nt < 8; ++Nt)
                        acc3[Mt][Nt] = (float4v){b2v[Nt], b2v[Nt], b2v[Nt], b2v[Nt]};
                #pragma unroll
                for (int Ks = 0; Ks < 4; ++Ks) {
                    short8 a2[2];
                    #pragma unroll
                    for (int Mt = 0; Mt < 2; ++Mt)
                        a2[Mt] = *(const short8*)&zw[(Mt*16 + ln)*136 + Ks*32 + q8*8];
                    #pragma unroll
                    for (int Nt = 0; Nt < 8; ++Nt) {
                        short8 bf = ldw(w2f, (Nt*4 + Ks)*64 + l);
                        #pragma unroll
                        for (int Mt = 0; Mt < 2; ++Mt)
                            acc3[Mt][Nt] = __builtin_amdgcn_mfma_f32_16x16x32_bf16(
                                a2[Mt], bf, acc3[Mt][Nt], 0, 0, 0);
                    }
                }

                float mm[8];
                #pragma unroll
                for (int Nt = 0; Nt < 8; ++Nt) {
                    const bool pos = g2v[Nt] >= 0.f;
                    float m = acc3[0][Nt][0];
                    #pragma unroll
                    for (int Mt = 0; Mt < 2; ++Mt)
                        #pragma unroll
                        for (int r = 0; r < 4; ++r) {
                            float h = acc3[Mt][Nt][r];
                            s[Nt] += h; sq[Nt] += h*h;
                            if (!(Mt == 0 && r == 0))
                                m = pos ? fmaxf(m, h) : fminf(m, h);
                        }
                    float o = __shfl_xor(m, 16); m = pos ? fmaxf(m, o) : fminf(m, o);
                    o = __shfl_xor(m, 32);       m = pos ? fmaxf(m, o) : fminf(m, o);
                    mm[Nt] = m;
                }
                if (l < 16) {
                    #pragma unroll
                    for (int Nt = 0; Nt < 8; ++Nt)
                        out_pts[(long)g*128 + Nt*16 + l] = mm[Nt];
                }
            }
        }
    }

    constexpr int NT = (STAGE == 3) ? 8 : 4;
    constexpr int soff = (STAGE == 1) ? 0 : (STAGE == 2) ? 128 : 256;
    constexpr int qoff = (STAGE == 1) ? 64 : (STAGE == 2) ? 192 : 384;
    #pragma unroll
    for (int t = 0; t < NT; ++t) {
        float a = s[t], b = sq[t];
        a += __shfl_xor(a, 16); a += __shfl_xor(a, 32);
        b += __shfl_xor(b, 16); b += __shfl_xor(b, 32);
        if (l < 16) {
            atomicAdd(&sums[soff + t*16 + l], a);
            atomicAdd(&sums[qoff + t*16 + l], b);
        }
    }
}

// ---------------- finalize: mean/var -> BN scale/shift ----------------
__global__ void k_fin(const float* __restrict__ sums, const float* __restrict__ g,
                      const float* __restrict__ be, float* __restrict__ scl,
                      int sum_off, int sq_off, int sc_off, int sh_off, int C)
{
    int c = threadIdx.x;
    if (c < C) {
        float mean = sums[sum_off + c] * (1.0f / PP);
        float var  = sums[sq_off + c] * (1.0f / PP) - mean * mean;
        float s = g[c] * rsqrtf(var + EPSF);
        scl[sc_off + c] = s;
        scl[sh_off + c] = be[c] - mean * s;
    }
}

// ---------------- apply BN3+ReLU to the pooled pre-activations ----------------
__global__ void k_bnmax(float* __restrict__ op, const float* __restrict__ scl) {
    int i = blockIdx.x * 256 + threadIdx.x;
    int c = i & 127;
    float sc = scl[256 + c], sf = scl[384 + c];
    op[i] = fmaxf(fmaf(op[i], sc, sf), 0.f);
}

extern "C" void kernel_launch(void* const* d_in, const int* in_sizes, int n_in,
                              void* d_out, int out_size, void* d_ws, size_t ws_size,
                              hipStream_t stream) {
    const float* xyz = (const float*)d_in[0];
    const float* pts = (const float*)d_in[1];
    const int*   fps = (const int*)d_in[2];
    const float* w0  = (const float*)d_in[3];
    const float* b0  = (const float*)d_in[4];
    const float* g0  = (const float*)d_in[5];
    const float* be0 = (const float*)d_in[6];
    const float* w1  = (const float*)d_in[7];
    const float* b1  = (const float*)d_in[8];
    const float* g1  = (const float*)d_in[9];
    const float* be1 = (const float*)d_in[10];
    const float* w2  = (const float*)d_in[11];
    const float* b2  = (const float*)d_in[12];
    const float* g2  = (const float*)d_in[13];
    const float* be2 = (const float*)d_in[14];

    float* ws = (float*)d_ws;
    float* out_xyz = (float*)d_out;
    float* out_pts = (float*)d_out + NG * 3;

    k_prep<<<1, 256, 0, stream>>>(w0, w1, w2, ws);
    k_select<<<NG / QPB, 512, 0, stream>>>(xyz, fps, out_xyz, ws);

    if (ws_size >= WS_FAST_BYTES) {
        ushort* h1 = (ushort*)(ws + WS_H1);
        ushort* h2 = (ushort*)(ws + WS_H2);
        k_g1<<<1024, 256, 0, stream>>>(xyz, pts, b0, ws, h1);
        k_fin<<<1, 128, 0, stream>>>(ws + WS_SUMS, g0, be0, ws + WS_SCALE, 0, 64, 0, 64, 64);
        k_g2<<<1024, 256, 0, stream>>>(b1, ws, h1, h2);
        k_fin<<<1, 128, 0, stream>>>(ws + WS_SUMS, g1, be1, ws + WS_SCALE, 128, 192, 128, 192, 64);
        k_g3<<<1024, 256, 0, stream>>>(b2, g2, ws, h2, out_pts);
        k_fin<<<1, 128, 0, stream>>>(ws + WS_SUMS, g2, be2, ws + WS_SCALE, 256, 384, 256, 384, 128);
    } else {
        k_passF<1><<<1024, 256, 0, stream>>>(xyz, pts, b0, b1, b2, g2, ws, out_pts);
        k_fin<<<1, 128, 0, stream>>>(ws + WS_SUMS, g0, be0, ws + WS_SCALE, 0, 64, 0, 64, 64);
        k_passF<2><<<1024, 256, 0, stream>>>(xyz, pts, b0, b1, b2, g2, ws, out_pts);
        k_fin<<<1, 128, 0, stream>>>(ws + WS_SUMS, g1, be1, ws + WS_SCALE, 128, 192, 128, 192, 64);
        k_passF<3><<<1024, 256, 0, stream>>>(xyz, pts, b0, b1, b2, g2, ws, out_pts);
        k_fin<<<1, 128, 0, stream>>>(ws + WS_SUMS, g2, be2, ws + WS_SCALE, 256, 384, 256, 384, 128);
    }
    k_bnmax<<<NG * 128 / 256, 256, 0, stream>>>(out_pts, ws + WS_SCALE);
}